// Round 1
// baseline (6760.658 us; speedup 1.0000x reference)
//
#include <hip/hip_runtime.h>
#include <cstddef>

#define L_SEQ   2048
#define D_MODEL 2048
#define NHEADS  16
#define DHEAD   128
#define NBH     64        // B*H
#define M_ROWS  8192      // B*L

// ======================= GEMM: C = A * W^T =======================
// A: (M_ROWS, 2048) ; W: (2048, 2048) row-major (nn.Linear weight).
// A_MODE  0: plain row-major   1: A stored as (B,H,L,DHEAD)
// OUT_MODE 0: plain row-major C 1: C written as (B,H,L,DHEAD)
template<int A_MODE, int OUT_MODE>
__global__ __launch_bounds__(256)
void gemm_nt(const float* __restrict__ A, const float* __restrict__ W,
             float* __restrict__ C) {
  __shared__ float As[16][68];
  __shared__ float Bs[16][68];
  const int tid  = threadIdx.x;
  const int rBase = blockIdx.x << 6;
  const int cBase = blockIdx.y << 6;
  const int lrow = tid >> 2;          // 0..63
  const int lk4  = (tid & 3) << 2;    // 0,4,8,12
  const int ty   = tid >> 4;          // 0..15
  const int tx   = tid & 15;

  float acc[4][4] = {};

  for (int kb = 0; kb < D_MODEL; kb += 16) {
    size_t a_idx;
    if (A_MODE == 0) {
      a_idx = (size_t)(rBase + lrow) * D_MODEL + kb + lk4;
    } else {
      const int gr = rBase + lrow;
      const int bb = gr >> 11, l = gr & 2047;
      const int kc = kb + lk4;
      const int h = kc >> 7, p = kc & 127;
      a_idx = (((size_t)(bb * NHEADS + h)) * L_SEQ + l) * DHEAD + p;
    }
    const float4 av = *(const float4*)(A + a_idx);
    const float4 bv = *(const float4*)(W + (size_t)(cBase + lrow) * D_MODEL + kb + lk4);
    __syncthreads();   // protect LDS from previous iteration's readers
    As[lk4 + 0][lrow] = av.x; As[lk4 + 1][lrow] = av.y;
    As[lk4 + 2][lrow] = av.z; As[lk4 + 3][lrow] = av.w;
    Bs[lk4 + 0][lrow] = bv.x; Bs[lk4 + 1][lrow] = bv.y;
    Bs[lk4 + 2][lrow] = bv.z; Bs[lk4 + 3][lrow] = bv.w;
    __syncthreads();
#pragma unroll
    for (int kk = 0; kk < 16; ++kk) {
      const float4 a4 = *(const float4*)(&As[kk][ty << 2]);
      const float4 b4 = *(const float4*)(&Bs[kk][tx << 2]);
      const float ar[4] = {a4.x, a4.y, a4.z, a4.w};
      const float br[4] = {b4.x, b4.y, b4.z, b4.w};
#pragma unroll
      for (int i = 0; i < 4; ++i)
#pragma unroll
        for (int j = 0; j < 4; ++j)
          acc[i][j] = fmaf(ar[i], br[j], acc[i][j]);
    }
  }

#pragma unroll
  for (int i = 0; i < 4; ++i) {
    const int r  = rBase + (ty << 2) + i;
    const int c0 = cBase + (tx << 2);
    float4 v;
    v.x = acc[i][0]; v.y = acc[i][1]; v.z = acc[i][2]; v.w = acc[i][3];
    if (OUT_MODE == 0) {
      *(float4*)(C + (size_t)r * D_MODEL + c0) = v;
    } else {
      const int bb = r >> 11, l = r & 2047;
      const int h = c0 >> 7, p = c0 & 127;
      *(float4*)(C + (((size_t)(bb * NHEADS + h)) * L_SEQ + l) * DHEAD + p) = v;
    }
  }
}

// ======================= RoPE + sigmoid (in place on Q,K) =======================
// thread handles pair (p, p+64) of one (b,h,l) row; both share the same angle.
__global__ __launch_bounds__(256)
void rope_sigmoid(float* __restrict__ Q, float* __restrict__ Kb) {
  const int t = blockIdx.x * 256 + threadIdx.x;   // 0 .. NBH*L_SEQ*64-1
  float* buf = (blockIdx.y == 0) ? Q : Kb;
  const int p  = t & 63;
  const int l  = (t >> 6) & 2047;
  const int bh = t >> 17;
  const size_t base = ((size_t)bh * L_SEQ + l) * DHEAD;
  const float v1 = buf[base + p];
  const float v2 = buf[base + p + 64];
  const float inv_freq = 1.0f / powf(10000.0f, (float)p * (1.0f / 64.0f));
  const float ang = (float)l * inv_freq;
  float s, c;
  sincosf(ang, &s, &c);
  float o1 = v1 * c - v2 * s;       // p < 64 : x1*cos - x2*sin
  float o2 = v2 * c + v1 * s;       // p >= 64: x2*cos + x1*sin
  o1 = 1.0f / (1.0f + expf(-o1));
  o2 = 1.0f / (1.0f + expf(-o2));
  buf[base + p]      = o1;
  buf[base + p + 64] = o2;
}

// ======================= causal flash attention =======================
// scores = (2*q.k - |q|^2 - |k|^2)/tau, causal, online softmax, O = P V / l
#define BQ 64
#define KT 32
__global__ __launch_bounds__(256)
void attn_causal(const float* __restrict__ Q, const float* __restrict__ K,
                 const float* __restrict__ V, const float* __restrict__ tau_p,
                 float* __restrict__ O) {
  __shared__ float Qs[BQ][DHEAD + 4];
  __shared__ float Ks[KT][DHEAD + 4];
  __shared__ float Vs[KT][DHEAD + 4];
  __shared__ float Ss[BQ][KT + 1];
  __shared__ float qsq[BQ], ksq[KT], row_m[BQ], row_l[BQ], row_a[BQ];

  const int qt = blockIdx.x, bh = blockIdx.y;
  const int tid = threadIdx.x;
  const int ty = tid >> 4, tx = tid & 15;

  const float* Qh = Q + ((size_t)bh * L_SEQ + (size_t)qt * BQ) * DHEAD;
  const float* Kh = K + (size_t)bh * L_SEQ * DHEAD;
  const float* Vh = V + (size_t)bh * L_SEQ * DHEAD;

  for (int i = tid; i < BQ * DHEAD / 4; i += 256) {
    const int r = i >> 5, c4 = (i & 31) << 2;
    *(float4*)(&Qs[r][c4]) = *(const float4*)(Qh + (size_t)r * DHEAD + c4);
  }
  __syncthreads();
  if (tid < BQ) {
    float s = 0.f;
#pragma unroll
    for (int p = 0; p < DHEAD; p += 4) {
      const float4 q4 = *(const float4*)(&Qs[tid][p]);
      s += q4.x * q4.x + q4.y * q4.y + q4.z * q4.z + q4.w * q4.w;
    }
    qsq[tid] = s; row_m[tid] = -1e30f; row_l[tid] = 0.f;
  }
  const float traw = *tau_p;
  float tau = log1pf(expf(traw));
  tau = fminf(fmaxf(tau, 0.1f), 10.f);
  const float inv_tau = 1.f / tau;

  float o_acc[4][8];
#pragma unroll
  for (int i = 0; i < 4; ++i)
#pragma unroll
    for (int j = 0; j < 8; ++j) o_acc[i][j] = 0.f;

  const int r0 = ty << 2;   // S row base
  const int c0 = tx << 1;   // S col base
  const int p0 = tx << 3;   // O col base

  const int nkt = (qt + 1) * (BQ / KT);
  for (int kt = 0; kt < nkt; ++kt) {
    __syncthreads();  // previous iter's Ks/Vs/Ss readers are done
    for (int i = tid; i < KT * DHEAD / 4; i += 256) {
      const int r = i >> 5, c4 = (i & 31) << 2;
      *(float4*)(&Ks[r][c4]) = *(const float4*)(Kh + (size_t)(kt * KT + r) * DHEAD + c4);
      *(float4*)(&Vs[r][c4]) = *(const float4*)(Vh + (size_t)(kt * KT + r) * DHEAD + c4);
    }
    __syncthreads();
    if (tid < KT) {
      float s = 0.f;
#pragma unroll
      for (int p = 0; p < DHEAD; p += 4) {
        const float4 k4 = *(const float4*)(&Ks[tid][p]);
        s += k4.x * k4.x + k4.y * k4.y + k4.z * k4.z + k4.w * k4.w;
      }
      ksq[tid] = s;
    }
    // S = Q K^T (4x2 per thread)
    float acc[4][2] = {};
    for (int kk = 0; kk < DHEAD; kk += 4) {
      float4 a[4], b[2];
#pragma unroll
      for (int i = 0; i < 4; ++i) a[i] = *(const float4*)(&Qs[r0 + i][kk]);
#pragma unroll
      for (int j = 0; j < 2; ++j) b[j] = *(const float4*)(&Ks[c0 + j][kk]);
#pragma unroll
      for (int i = 0; i < 4; ++i)
#pragma unroll
        for (int j = 0; j < 2; ++j) {
          acc[i][j] = fmaf(a[i].x, b[j].x, acc[i][j]);
          acc[i][j] = fmaf(a[i].y, b[j].y, acc[i][j]);
          acc[i][j] = fmaf(a[i].z, b[j].z, acc[i][j]);
          acc[i][j] = fmaf(a[i].w, b[j].w, acc[i][j]);
        }
    }
    __syncthreads();  // ksq visible; Ss free
#pragma unroll
    for (int i = 0; i < 4; ++i)
#pragma unroll
      for (int j = 0; j < 2; ++j) {
        const int gr = (qt << 6) + r0 + i;
        const int gc = kt * KT + c0 + j;
        float s = (2.f * acc[i][j] - qsq[r0 + i] - ksq[c0 + j]) * inv_tau;
        if (gc > gr) s = -1e30f;
        Ss[r0 + i][c0 + j] = s;
      }
    __syncthreads();
    if (tid < BQ) {
      const float mo = row_m[tid];
      float mt = mo;
      for (int c = 0; c < KT; ++c) mt = fmaxf(mt, Ss[tid][c]);
      row_a[tid] = expf(mo - mt);
      row_m[tid] = mt;
    }
    __syncthreads();
#pragma unroll
    for (int i = 0; i < 4; ++i)
#pragma unroll
      for (int j = 0; j < 2; ++j)
        Ss[r0 + i][c0 + j] = expf(Ss[r0 + i][c0 + j] - row_m[r0 + i]);
    __syncthreads();
    if (tid < BQ) {
      float s = 0.f;
      for (int c = 0; c < KT; ++c) s += Ss[tid][c];
      row_l[tid] = row_l[tid] * row_a[tid] + s;
    }
#pragma unroll
    for (int i = 0; i < 4; ++i) {
      const float al = row_a[r0 + i];
#pragma unroll
      for (int j = 0; j < 8; ++j) o_acc[i][j] *= al;
    }
    for (int c = 0; c < KT; ++c) {
      float pr[4];
#pragma unroll
      for (int i = 0; i < 4; ++i) pr[i] = Ss[r0 + i][c];
      const float4 v0 = *(const float4*)(&Vs[c][p0]);
      const float4 v1 = *(const float4*)(&Vs[c][p0 + 4]);
      const float vv[8] = {v0.x, v0.y, v0.z, v0.w, v1.x, v1.y, v1.z, v1.w};
#pragma unroll
      for (int i = 0; i < 4; ++i)
#pragma unroll
        for (int j = 0; j < 8; ++j)
          o_acc[i][j] = fmaf(pr[i], vv[j], o_acc[i][j]);
    }
  }
  __syncthreads();  // row_l final
#pragma unroll
  for (int i = 0; i < 4; ++i) {
    const float invl = 1.f / row_l[r0 + i];
    const int gr = (qt << 6) + r0 + i;
    float4 w0, w1;
    w0.x = o_acc[i][0] * invl; w0.y = o_acc[i][1] * invl;
    w0.z = o_acc[i][2] * invl; w0.w = o_acc[i][3] * invl;
    w1.x = o_acc[i][4] * invl; w1.y = o_acc[i][5] * invl;
    w1.z = o_acc[i][6] * invl; w1.w = o_acc[i][7] * invl;
    float* dst = O + ((size_t)bh * L_SEQ + gr) * DHEAD + p0;
    *(float4*)dst = w0;
    *(float4*)(dst + 4) = w1;
  }
}

// ======================= launch =======================
extern "C" void kernel_launch(void* const* d_in, const int* in_sizes, int n_in,
                              void* d_out, int out_size, void* d_ws, size_t ws_size,
                              hipStream_t stream) {
  const float* x     = (const float*)d_in[0];
  const float* Wq    = (const float*)d_in[1];
  const float* Wk    = (const float*)d_in[2];
  const float* Wv    = (const float*)d_in[3];
  const float* Wo    = (const float*)d_in[4];
  const float* tau_p = (const float*)d_in[5];
  // d_in[6] = mask (unused; causality applied structurally)

  float* ws = (float*)d_ws;
  const size_t NELEM = (size_t)M_ROWS * D_MODEL;   // 16,777,216
  float* Qb = ws;                 // (B,H,L,d) — later aliased as attention O
  float* Kb = ws + NELEM;
  float* Vb = ws + 2 * NELEM;
  float* out = (float*)d_out;

  const dim3 gGemm(M_ROWS / 64, D_MODEL / 64);  // (128, 32)
  gemm_nt<0, 1><<<gGemm, 256, 0, stream>>>(x, Wq, Qb);
  gemm_nt<0, 1><<<gGemm, 256, 0, stream>>>(x, Wk, Kb);
  gemm_nt<0, 1><<<gGemm, 256, 0, stream>>>(x, Wv, Vb);

  const dim3 gRope((NBH * L_SEQ * 64) / 256, 2);  // (32768, 2)
  rope_sigmoid<<<gRope, 256, 0, stream>>>(Qb, Kb);

  const dim3 gAttn(L_SEQ / BQ, NBH);  // (32, 64)
  attn_causal<<<gAttn, 256, 0, stream>>>(Qb, Kb, Vb, tau_p, /*O=*/Qb);

  gemm_nt<1, 0><<<gGemm, 256, 0, stream>>>(Qb, Wo, out);
}

// Round 2
// 965.610 us; speedup vs baseline: 7.0014x; 7.0014x over previous
//
#include <hip/hip_runtime.h>
#include <cstddef>

typedef unsigned short u16;
typedef unsigned int   u32;
typedef short  bf16x8 __attribute__((ext_vector_type(8)));
typedef float  f32x4  __attribute__((ext_vector_type(4)));

#define L_SEQ   2048
#define D_MODEL 2048
#define NHEADS  16
#define DHEAD   128
#define NBH     64
#define M_ROWS  8192

__device__ __forceinline__ u16 f2bf(float f) {
  u32 u = __float_as_uint(f);
  u32 r = (u + 0x7FFFu + ((u >> 16) & 1u)) >> 16;   // RNE; inputs are finite
  return (u16)r;
}
__device__ __forceinline__ float bf2f(u16 u) {
  return __uint_as_float(((u32)u) << 16);
}
__device__ __forceinline__ void load_lds16(const u16* g, u16* l) {
  __builtin_amdgcn_global_load_lds((const __attribute__((address_space(1))) u32*)g,
                                   (__attribute__((address_space(3))) u32*)l, 16, 0, 0);
}

// ======================= fp32 -> bf16 cast =======================
__global__ __launch_bounds__(256) void cast_bf16(const float* __restrict__ s,
                                                 u16* __restrict__ d, int n4) {
  int i = blockIdx.x * 256 + threadIdx.x;
  if (i >= n4) return;
  float4 v = ((const float4*)s)[i];
  ushort4 o;
  o.x = f2bf(v.x); o.y = f2bf(v.y); o.z = f2bf(v.z); o.w = f2bf(v.w);
  ((ushort4*)d)[i] = o;
}

// ======================= bf16 MFMA GEMM: C = A * W^T =======================
// A: (M,2048) bf16 row-major; W: (2048,2048) bf16 row-major (nn.Linear weight).
// 128x128 tile, BK=64, 4 waves (2x2), each wave 4x4 MFMA 16x16x32 tiles.
// LDS tiles stored with XOR chunk swizzle: logical (row n, 16B-chunk c of 8)
// lives at phys chunk c ^ (n&7)  -> conflict-free(ish) ds_read_b128.
// OUT_MODE 0: f32 row-major; 1: bf16 (B,H,L,d)
template<int OUT_MODE>
__global__ __launch_bounds__(256)
void gemm_bt(const u16* __restrict__ A, const u16* __restrict__ W, void* __restrict__ C) {
  __shared__ __align__(16) u16 As[128 * 64];
  __shared__ __align__(16) u16 Bs[128 * 64];
  const int tid  = threadIdx.x;
  const int wave = tid >> 6, lane = tid & 63;
  const int quad = lane >> 4, l15 = lane & 15;
  const int wr = wave >> 1, wc = wave & 1;
  const int rBase = blockIdx.x << 7;
  const int cBase = blockIdx.y << 7;

  f32x4 acc[4][4];
#pragma unroll
  for (int m = 0; m < 4; ++m)
#pragma unroll
    for (int n = 0; n < 4; ++n) acc[m][n] = (f32x4){0.f, 0.f, 0.f, 0.f};

  for (int kb = 0; kb < D_MODEL; kb += 64) {
    __syncthreads();   // prior iteration's LDS readers done
#pragma unroll
    for (int i = 0; i < 4; ++i) {
      const int s = (wave * 4 + i) * 64 + lane;     // 16B slot 0..1023
      const int n = s >> 3;                          // tile row
      const int c = (s & 7) ^ (n & 7);               // source chunk (swizzle)
      load_lds16(A + (size_t)(rBase + n) * D_MODEL + kb + c * 8,
                 As + (size_t)(wave * 4 + i) * 512);
      load_lds16(W + (size_t)(cBase + n) * D_MODEL + kb + c * 8,
                 Bs + (size_t)(wave * 4 + i) * 512);
    }
    __syncthreads();   // drains vmcnt: staged data visible

#pragma unroll
    for (int h = 0; h < 2; ++h) {
      bf16x8 af[4], bfr[4];
#pragma unroll
      for (int m = 0; m < 4; ++m) {
        const int row = wr * 64 + m * 16 + l15;
        const int cc = (h * 4 + quad) ^ (row & 7);
        af[m] = *(const bf16x8*)(As + row * 64 + cc * 8);
      }
#pragma unroll
      for (int n = 0; n < 4; ++n) {
        const int row = wc * 64 + n * 16 + l15;
        const int cc = (h * 4 + quad) ^ (row & 7);
        bfr[n] = *(const bf16x8*)(Bs + row * 64 + cc * 8);
      }
#pragma unroll
      for (int m = 0; m < 4; ++m)
#pragma unroll
        for (int n = 0; n < 4; ++n)
          acc[m][n] = __builtin_amdgcn_mfma_f32_16x16x32_bf16(af[m], bfr[n], acc[m][n], 0, 0, 0);
    }
  }

  // epilogue: C/D layout col = lane&15, row = quad*4 + reg
#pragma unroll
  for (int m = 0; m < 4; ++m) {
#pragma unroll
    for (int n = 0; n < 4; ++n) {
      const int row0 = rBase + wr * 64 + m * 16 + quad * 4;
      const int col  = cBase + wc * 64 + n * 16 + l15;
#pragma unroll
      for (int r = 0; r < 4; ++r) {
        const float v = acc[m][n][r];
        if (OUT_MODE == 0) {
          ((float*)C)[(size_t)(row0 + r) * D_MODEL + col] = v;
        } else {
          const int rr = row0 + r;
          const int b = rr >> 11, l = rr & 2047;
          const int h = col >> 7, p = col & 127;
          ((u16*)C)[(((size_t)(b * NHEADS + h)) * L_SEQ + l) * DHEAD + p] = f2bf(v);
        }
      }
    }
  }
}

// ======================= RoPE + sigmoid (bf16 in/out) + row square-sums =======================
// thread: pair (p, p+64) of one (bh,l) row; wave = one row; wave-reduce sum of squares.
__global__ __launch_bounds__(256)
void rope_sig(u16* __restrict__ Q, u16* __restrict__ K,
              float* __restrict__ qsq, float* __restrict__ ksq) {
  const int t = blockIdx.x * 256 + threadIdx.x;
  u16* buf = blockIdx.y ? K : Q;
  float* sq = blockIdx.y ? ksq : qsq;
  const int p  = t & 63;
  const int l  = (t >> 6) & 2047;
  const int bh = t >> 17;
  const size_t base = ((size_t)bh * L_SEQ + l) * DHEAD;
  const float v1 = bf2f(buf[base + p]);
  const float v2 = bf2f(buf[base + p + 64]);
  const float invf = exp2f(-(float)p * (13.287712379549449f / 64.f));  // 10000^(-p/64)
  const float ang = (float)l * invf;
  float s, c;
  sincosf(ang, &s, &c);
  float o1 = v1 * c - v2 * s;
  float o2 = v2 * c + v1 * s;
  o1 = 1.f / (1.f + __expf(-o1));
  o2 = 1.f / (1.f + __expf(-o2));
  const u16 b1 = f2bf(o1), b2 = f2bf(o2);
  buf[base + p]      = b1;
  buf[base + p + 64] = b2;
  const float r1 = bf2f(b1), r2 = bf2f(b2);   // square the *stored* values
  float ss = r1 * r1 + r2 * r2;
#pragma unroll
  for (int off = 1; off < 64; off <<= 1) ss += __shfl_xor(ss, off, 64);
  if ((threadIdx.x & 63) == 0) sq[(size_t)bh * L_SEQ + l] = ss;
}

// ======================= MFMA flash attention =======================
// scores = (2 q.k - |q|^2 - |k|^2)/tau, causal, online softmax. BQ=KT=64.
// 4 waves; wave owns 16 q rows. Q A-frags in regs. K staged swizzled via
// global_load_lds; V transposed to Vt[n][k] (pitch 72) at staging; P round-trips
// through wave-private f32 LDS (C-layout -> A-layout).
__global__ __launch_bounds__(256)
void attn_mfma(const u16* __restrict__ Q, const u16* __restrict__ K, const u16* __restrict__ V,
               const float* __restrict__ qsq_g, const float* __restrict__ ksq_g,
               const float* __restrict__ taup, u16* __restrict__ Ob) {
  __shared__ __align__(16) u16  Ks[64 * 128];        // swizzled: chunk c ^ (n&15)
  __shared__ __align__(16) u16  Vt[128 * 72];        // [n=0..127][k=0..63], pitch 72
  __shared__ __align__(16) float Pls[4][16 * 68];    // per-wave P, pitch 68 f32
  __shared__ float qsqs[64], ksqs[64];

  const int qt = (int)gridDim.x - 1 - (int)blockIdx.x;   // big tiles first
  const int bh = blockIdx.y;
  const int tid = threadIdx.x;
  const int wave = tid >> 6, lane = tid & 63;
  const int quad = lane >> 4, l15 = lane & 15;
  const int qBase = qt * 64;

  // Q fragments (A-layout: m = lane&15, k = quad*8+j), 4 k-blocks of 32
  const u16* Qrow = Q + ((size_t)bh * L_SEQ + qBase + wave * 16 + l15) * DHEAD;
  bf16x8 aq[4];
#pragma unroll
  for (int kb = 0; kb < 4; ++kb) aq[kb] = *(const bf16x8*)(Qrow + kb * 32 + quad * 8);

  if (tid < 64) qsqs[tid] = qsq_g[(size_t)bh * L_SEQ + qBase + tid];

  float tau = log1pf(expf(*taup));
  tau = fminf(fmaxf(tau, 0.1f), 10.f);
  const float inv_tau = 1.f / tau;

  float mst[4] = {-1e30f, -1e30f, -1e30f, -1e30f};
  float lst[4] = {0.f, 0.f, 0.f, 0.f};
  f32x4 oacc[8];
#pragma unroll
  for (int i = 0; i < 8; ++i) oacc[i] = (f32x4){0.f, 0.f, 0.f, 0.f};

  const int mrow = quad * 4;                      // this lane's C-layout row base
  const int qg0 = qBase + wave * 16 + mrow;       // global q row for reg r -> qg0+r

  for (int kt = 0; kt <= qt; ++kt) {
    __syncthreads();   // prior iteration's Ks/Vt readers done
    // ---- stage K tile (swizzled DMA) ----
    const u16* Ktile = K + ((size_t)bh * L_SEQ + kt * 64) * DHEAD;
#pragma unroll
    for (int i = 0; i < 4; ++i) {
      const int s = (wave * 4 + i) * 64 + lane;   // 16B slot 0..1023
      const int n = s >> 4;                        // key row 0..63 (16 chunks/row)
      const int c = (s & 15) ^ (n & 15);
      load_lds16(Ktile + n * DHEAD + c * 8, Ks + (size_t)(wave * 4 + i) * 512);
    }
    // ---- stage V transposed ----
    const u16* Vtile = V + ((size_t)bh * L_SEQ + kt * 64) * DHEAD;
#pragma unroll
    for (int a = 0; a < 2; ++a) {
      const int idx = a * 256 + tid;              // 0..511
      const int kp = idx & 31;                    // k pair -> k0 = 2*kp
      const int n0 = (idx >> 5) * 8;              // n chunk base
      const u16* vr = Vtile + (size_t)(2 * kp) * DHEAD + n0;
      const bf16x8 r0 = *(const bf16x8*)vr;
      const bf16x8 r1 = *(const bf16x8*)(vr + DHEAD);
#pragma unroll
      for (int j = 0; j < 8; ++j) {
        const u32 pack = (u32)(u16)r0[j] | ((u32)(u16)r1[j] << 16);
        *(u32*)&Vt[(n0 + j) * 72 + 2 * kp] = pack;
      }
    }
    if (tid < 64) ksqs[tid] = ksq_g[(size_t)bh * L_SEQ + kt * 64 + tid];
    __syncthreads();   // staged K/V/ksq visible

    // ---- S = Q K^T ----
    f32x4 sfr[4];
#pragma unroll
    for (int nt = 0; nt < 4; ++nt) {
      f32x4 cacc = (f32x4){0.f, 0.f, 0.f, 0.f};
      const int brow = nt * 16 + l15;             // key within tile
#pragma unroll
      for (int kb = 0; kb < 4; ++kb) {
        const int cc = (kb * 4 + quad) ^ (brow & 15);
        const bf16x8 bf = *(const bf16x8*)(Ks + brow * 128 + cc * 8);
        cacc = __builtin_amdgcn_mfma_f32_16x16x32_bf16(aq[kb], bf, cacc, 0, 0, 0);
      }
      sfr[nt] = cacc;
    }

    // ---- transform + mask + online softmax ----
    float qs[4];
#pragma unroll
    for (int r = 0; r < 4; ++r) qs[r] = qsqs[wave * 16 + mrow + r];
    const bool diag = (kt == qt);
    float mx[4] = {-1e30f, -1e30f, -1e30f, -1e30f};
#pragma unroll
    for (int nt = 0; nt < 4; ++nt) {
      const float ksn = ksqs[nt * 16 + l15];
      const int kg = kt * 64 + nt * 16 + l15;
#pragma unroll
      for (int r = 0; r < 4; ++r) {
        float sv = (2.f * sfr[nt][r] - qs[r] - ksn) * inv_tau;
        if (diag && kg > qg0 + r) sv = -1e30f;
        sfr[nt][r] = sv;
        mx[r] = fmaxf(mx[r], sv);
      }
    }
#pragma unroll
    for (int off = 1; off < 16; off <<= 1)
#pragma unroll
      for (int r = 0; r < 4; ++r) mx[r] = fmaxf(mx[r], __shfl_xor(mx[r], off, 64));

    float al[4], rs[4] = {0.f, 0.f, 0.f, 0.f};
#pragma unroll
    for (int r = 0; r < 4; ++r) {
      const float mn = fmaxf(mst[r], mx[r]);
      al[r] = __expf(mst[r] - mn);
      mst[r] = mn;
    }
#pragma unroll
    for (int nt = 0; nt < 4; ++nt)
#pragma unroll
      for (int r = 0; r < 4; ++r) {
        const float pv = __expf(sfr[nt][r] - mst[r]);
        sfr[nt][r] = pv;
        rs[r] += pv;
      }
#pragma unroll
    for (int off = 1; off < 16; off <<= 1)
#pragma unroll
      for (int r = 0; r < 4; ++r) rs[r] += __shfl_xor(rs[r], off, 64);
#pragma unroll
    for (int r = 0; r < 4; ++r) lst[r] = lst[r] * al[r] + rs[r];
#pragma unroll
    for (int t = 0; t < 8; ++t)
#pragma unroll
      for (int r = 0; r < 4; ++r) oacc[t][r] *= al[r];

    // ---- P: C-layout -> wave-private LDS (f32) -> A-layout bf16 frags ----
    float* Pw = &Pls[wave][0];
#pragma unroll
    for (int nt = 0; nt < 4; ++nt)
#pragma unroll
      for (int r = 0; r < 4; ++r)
        Pw[(mrow + r) * 68 + nt * 16 + l15] = sfr[nt][r];
    __asm__ __volatile__("s_waitcnt lgkmcnt(0)" ::: "memory");
    bf16x8 pf[2];
#pragma unroll
    for (int kb = 0; kb < 2; ++kb) {
      const f32x4 p0 = *(const f32x4*)&Pw[l15 * 68 + kb * 32 + quad * 8];
      const f32x4 p1 = *(const f32x4*)&Pw[l15 * 68 + kb * 32 + quad * 8 + 4];
#pragma unroll
      for (int j = 0; j < 4; ++j) {
        pf[kb][j]     = (short)f2bf(p0[j]);
        pf[kb][j + 4] = (short)f2bf(p1[j]);
      }
    }
    // ---- O += P V ----
#pragma unroll
    for (int ot = 0; ot < 8; ++ot) {
#pragma unroll
      for (int kb = 0; kb < 2; ++kb) {
        const bf16x8 vf = *(const bf16x8*)(Vt + (ot * 16 + l15) * 72 + kb * 32 + quad * 8);
        oacc[ot] = __builtin_amdgcn_mfma_f32_16x16x32_bf16(pf[kb], vf, oacc[ot], 0, 0, 0);
      }
    }
  }

  // ---- epilogue: O/l -> bf16 row-major (B,L,D) ----
  const int b = bh >> 4, hh = bh & 15;
#pragma unroll
  for (int r = 0; r < 4; ++r) {
    const float invl = 1.f / lst[r];
    const int qg = qg0 + r;
    u16* dst = Ob + ((size_t)(b * L_SEQ + qg)) * D_MODEL + hh * DHEAD;
#pragma unroll
    for (int ot = 0; ot < 8; ++ot)
      dst[ot * 16 + l15] = f2bf(oacc[ot][r] * invl);
  }
}

// ======================= launch =======================
extern "C" void kernel_launch(void* const* d_in, const int* in_sizes, int n_in,
                              void* d_out, int out_size, void* d_ws, size_t ws_size,
                              hipStream_t stream) {
  const float* x     = (const float*)d_in[0];
  const float* Wq    = (const float*)d_in[1];
  const float* Wk    = (const float*)d_in[2];
  const float* Wv    = (const float*)d_in[3];
  const float* Wo    = (const float*)d_in[4];
  const float* tau_p = (const float*)d_in[5];

  const size_t NX = (size_t)M_ROWS * D_MODEL;        // 16,777,216
  const size_t NW = (size_t)D_MODEL * D_MODEL / 2;   // wait: full weight is D*D
  (void)NW;
  u16* xb  = (u16*)d_ws;                             // also reused as Ob after GEMMs
  u16* Wqb = xb  + NX;
  u16* Wkb = Wqb + (size_t)D_MODEL * D_MODEL;
  u16* Wvb = Wkb + (size_t)D_MODEL * D_MODEL;
  u16* Wob = Wvb + (size_t)D_MODEL * D_MODEL;
  u16* Qb  = Wob + (size_t)D_MODEL * D_MODEL;
  u16* Kb  = Qb + NX;
  u16* Vb  = Kb + NX;
  float* qsq = (float*)(Vb + NX);
  float* ksq = qsq + (size_t)NBH * L_SEQ;
  u16* Obuf = xb;   // alias: x not needed after QKV projections

  // casts
  cast_bf16<<<dim3((int)(NX / 4 / 256)), 256, 0, stream>>>(x, xb, (int)(NX / 4));
  const int w4 = D_MODEL * D_MODEL / 4;
  cast_bf16<<<dim3(w4 / 256), 256, 0, stream>>>(Wq, Wqb, w4);
  cast_bf16<<<dim3(w4 / 256), 256, 0, stream>>>(Wk, Wkb, w4);
  cast_bf16<<<dim3(w4 / 256), 256, 0, stream>>>(Wv, Wvb, w4);
  cast_bf16<<<dim3(w4 / 256), 256, 0, stream>>>(Wo, Wob, w4);

  // projections -> (B,H,L,d) bf16
  const dim3 gGemm(M_ROWS / 128, D_MODEL / 128);   // (64,16)
  gemm_bt<1><<<gGemm, 256, 0, stream>>>(xb, Wqb, Qb);
  gemm_bt<1><<<gGemm, 256, 0, stream>>>(xb, Wkb, Kb);
  gemm_bt<1><<<gGemm, 256, 0, stream>>>(xb, Wvb, Vb);

  // rope + sigmoid + square sums
  const dim3 gRope((NBH * L_SEQ * 64) / 256, 2);
  rope_sig<<<gRope, 256, 0, stream>>>(Qb, Kb, qsq, ksq);

  // attention -> Obuf (B,L,D) bf16
  const dim3 gAttn(L_SEQ / 64, NBH);               // (32,64)
  attn_mfma<<<gAttn, 256, 0, stream>>>(Qb, Kb, Vb, qsq, ksq, tau_p, Obuf);

  // output projection -> f32
  gemm_bt<0><<<gGemm, 256, 0, stream>>>(Obuf, Wob, (float*)d_out);
}

// Round 3
// 824.136 us; speedup vs baseline: 8.2033x; 1.1717x over previous
//
#include <hip/hip_runtime.h>
#include <cstddef>

typedef unsigned short u16;
typedef unsigned int   u32;
typedef short  bf16x8 __attribute__((ext_vector_type(8)));
typedef float  f32x4  __attribute__((ext_vector_type(4)));

#define L_SEQ   2048
#define D_MODEL 2048
#define NHEADS  16
#define DHEAD   128
#define NBH     64
#define M_ROWS  8192
#define LOG2E   1.4426950408889634f

__device__ __forceinline__ u16 f2bf(float f) {
  u32 u = __float_as_uint(f);
  u32 r = (u + 0x7FFFu + ((u >> 16) & 1u)) >> 16;   // RNE; inputs finite
  return (u16)r;
}
__device__ __forceinline__ float bf2f(u16 u) {
  return __uint_as_float(((u32)u) << 16);
}
__device__ __forceinline__ void load_lds16(const u16* g, u16* l) {
  __builtin_amdgcn_global_load_lds((const __attribute__((address_space(1))) u32*)g,
                                   (__attribute__((address_space(3))) u32*)l, 16, 0, 0);
}

// ======================= fused fp32 -> bf16 casts =======================
// y=0: x (NX4 float4s); y=1..4: Wq,Wk,Wv,Wo (W4 float4s each)
__global__ __launch_bounds__(256)
void cast_all(const float* __restrict__ x,
              const float* __restrict__ wq, const float* __restrict__ wk,
              const float* __restrict__ wv, const float* __restrict__ wo,
              u16* __restrict__ xb, u16* __restrict__ wqb, u16* __restrict__ wkb,
              u16* __restrict__ wvb, u16* __restrict__ wob) {
  const int y = blockIdx.y;
  const float* s; u16* d; int n4;
  const int NX4 = M_ROWS * D_MODEL / 4;
  const int W4  = D_MODEL * D_MODEL / 4;
  switch (y) {
    case 0: s = x;  d = xb;  n4 = NX4; break;
    case 1: s = wq; d = wqb; n4 = W4;  break;
    case 2: s = wk; d = wkb; n4 = W4;  break;
    case 3: s = wv; d = wvb; n4 = W4;  break;
    default: s = wo; d = wob; n4 = W4; break;
  }
  int i = blockIdx.x * 256 + threadIdx.x;
  if (i >= n4) return;
  float4 v = ((const float4*)s)[i];
  ushort4 o;
  o.x = f2bf(v.x); o.y = f2bf(v.y); o.z = f2bf(v.z); o.w = f2bf(v.w);
  ((ushort4*)d)[i] = o;
}

// ======================= GEMM core: 128x128 tile, BK=64, bf16 MFMA =======================
// A (M,2048) bf16 row-major; W rows cBase..cBase+127 of a (2048,2048) bf16 matrix.
// LDS XOR chunk swizzle: logical (row n, chunk c of 8) at phys chunk c^(n&7).
__device__ __forceinline__ void gemm_core(const u16* __restrict__ A, const u16* __restrict__ W,
                                          u16* As, u16* Bs, int rBase, int cBase,
                                          f32x4 (&acc)[4][4]) {
  const int tid  = threadIdx.x;
  const int wave = tid >> 6, lane = tid & 63;
  const int quad = lane >> 4, l15 = lane & 15;
  const int wr = wave >> 1, wc = wave & 1;

#pragma unroll
  for (int m = 0; m < 4; ++m)
#pragma unroll
    for (int n = 0; n < 4; ++n) acc[m][n] = (f32x4){0.f, 0.f, 0.f, 0.f};

  for (int kb = 0; kb < D_MODEL; kb += 64) {
    __syncthreads();
#pragma unroll
    for (int i = 0; i < 4; ++i) {
      const int s = (wave * 4 + i) * 64 + lane;
      const int n = s >> 3;
      const int c = (s & 7) ^ (n & 7);
      load_lds16(A + (size_t)(rBase + n) * D_MODEL + kb + c * 8,
                 As + (size_t)(wave * 4 + i) * 512);
      load_lds16(W + (size_t)(cBase + n) * D_MODEL + kb + c * 8,
                 Bs + (size_t)(wave * 4 + i) * 512);
    }
    __syncthreads();
#pragma unroll
    for (int h = 0; h < 2; ++h) {
      bf16x8 af[4], bfr[4];
#pragma unroll
      for (int m = 0; m < 4; ++m) {
        const int row = wr * 64 + m * 16 + l15;
        const int cc = (h * 4 + quad) ^ (row & 7);
        af[m] = *(const bf16x8*)(As + row * 64 + cc * 8);
      }
#pragma unroll
      for (int n = 0; n < 4; ++n) {
        const int row = wc * 64 + n * 16 + l15;
        const int cc = (h * 4 + quad) ^ (row & 7);
        bfr[n] = *(const bf16x8*)(Bs + row * 64 + cc * 8);
      }
#pragma unroll
      for (int m = 0; m < 4; ++m)
#pragma unroll
        for (int n = 0; n < 4; ++n)
          acc[m][n] = __builtin_amdgcn_mfma_f32_16x16x32_bf16(af[m], bfr[n], acc[m][n], 0, 0, 0);
    }
  }
}

// ======================= fused QKV projection =======================
// grid (M/128, 48): blockIdx.y -> seg = y>>4 (0:Q 1:K 2:V), head h = y&15.
// Q,K -> (B,H,L,d) bf16.  V -> V^T (B,H,d,L) bf16 (LDS-transpose epilogue).
#define TP 136   // epilogue LDS tile pitch (u16)
__global__ __launch_bounds__(256)
void gemm_qkv(const u16* __restrict__ A,
              const u16* __restrict__ Wq, const u16* __restrict__ Wk, const u16* __restrict__ Wv,
              u16* __restrict__ Qo, u16* __restrict__ Ko, u16* __restrict__ Vt) {
  __shared__ __align__(16) u16 buf[128 * TP];   // 34,816 B; main loop uses first 32 KB
  u16* As = buf;
  u16* Bs = buf + 8192;

  const int tid  = threadIdx.x;
  const int wave = tid >> 6, lane = tid & 63;
  const int quad = lane >> 4, l15 = lane & 15;
  const int wr = wave >> 1, wc = wave & 1;
  const int rBase = blockIdx.x << 7;
  const int seg = blockIdx.y >> 4;
  const int h   = blockIdx.y & 15;
  const int cBase = h << 7;
  const u16* W = (seg == 0) ? Wq : (seg == 1) ? Wk : Wv;

  f32x4 acc[4][4];
  gemm_core(A, W, As, Bs, rBase, cBase, acc);

  __syncthreads();   // main loop LDS reads done; reuse buf as transpose tile
  if (seg < 2) {
    // T[l_loc][p_loc]
#pragma unroll
    for (int m = 0; m < 4; ++m)
#pragma unroll
      for (int n = 0; n < 4; ++n) {
        const int l0 = wr * 64 + m * 16 + quad * 4;
        const int p  = wc * 64 + n * 16 + l15;
#pragma unroll
        for (int r = 0; r < 4; ++r)
          buf[(l0 + r) * TP + p] = f2bf(acc[m][n][r]);
      }
  } else {
    // T[p_loc][l_loc], 4 consecutive l -> packed b64 store
#pragma unroll
    for (int m = 0; m < 4; ++m)
#pragma unroll
      for (int n = 0; n < 4; ++n) {
        const int l0 = wr * 64 + m * 16 + quad * 4;
        const int p  = wc * 64 + n * 16 + l15;
        uint2 pk;
        pk.x = (u32)f2bf(acc[m][n][0]) | ((u32)f2bf(acc[m][n][1]) << 16);
        pk.y = (u32)f2bf(acc[m][n][2]) | ((u32)f2bf(acc[m][n][3]) << 16);
        *(uint2*)&buf[p * TP + l0] = pk;
      }
  }
  __syncthreads();

  // store: thread t -> T row t>>1, half t&1 (64 u16 = 8 x b128)
  const int row = tid >> 1, hf = tid & 1;
  const u16* src = buf + row * TP + hf * 64;
  u16* dst;
  if (seg < 2) {
    const int token = rBase + row;
    const int b = token >> 11, l = token & 2047;
    u16* base = (seg == 0) ? Qo : Ko;
    dst = base + (((size_t)(b * NHEADS + h) * L_SEQ + l)) * DHEAD + hf * 64;
  } else {
    const int b = rBase >> 11, l0 = (rBase & 2047) + hf * 64;
    dst = Vt + ((size_t)(b * NHEADS + h) * DHEAD + row) * L_SEQ + l0;
  }
#pragma unroll
  for (int c = 0; c < 8; ++c)
    *(bf16x8*)(dst + c * 8) = *(const bf16x8*)(src + c * 8);
}

// ======================= output projection: C = A * Wo^T (f32 out) =======================
__global__ __launch_bounds__(256)
void gemm_out(const u16* __restrict__ A, const u16* __restrict__ W, float* __restrict__ C) {
  __shared__ __align__(16) u16 As[128 * 64];
  __shared__ __align__(16) u16 Bs[128 * 64];
  const int tid  = threadIdx.x;
  const int wave = tid >> 6, lane = tid & 63;
  const int quad = lane >> 4, l15 = lane & 15;
  const int wr = wave >> 1, wc = wave & 1;
  const int rBase = blockIdx.x << 7;
  const int cBase = blockIdx.y << 7;

  f32x4 acc[4][4];
  gemm_core(A, W, As, Bs, rBase, cBase, acc);

#pragma unroll
  for (int m = 0; m < 4; ++m)
#pragma unroll
    for (int n = 0; n < 4; ++n) {
      const int row0 = rBase + wr * 64 + m * 16 + quad * 4;
      const int col  = cBase + wc * 64 + n * 16 + l15;
#pragma unroll
      for (int r = 0; r < 4; ++r)
        C[(size_t)(row0 + r) * D_MODEL + col] = acc[m][n][r];
    }
}

// ======================= RoPE + sigmoid (bf16, in place) + row square-sums =======================
__global__ __launch_bounds__(256)
void rope_sig(u16* __restrict__ Q, u16* __restrict__ K,
              float* __restrict__ qsq, float* __restrict__ ksq) {
  const int t = blockIdx.x * 256 + threadIdx.x;
  u16* buf = blockIdx.y ? K : Q;
  float* sq = blockIdx.y ? ksq : qsq;
  const int p  = t & 63;
  const int l  = (t >> 6) & 2047;
  const int bh = t >> 17;
  const size_t base = ((size_t)bh * L_SEQ + l) * DHEAD;
  const float v1 = bf2f(buf[base + p]);
  const float v2 = bf2f(buf[base + p + 64]);
  const float invf = exp2f(-(float)p * (13.287712379549449f / 64.f));  // 10000^(-p/64)
  const float ang = (float)l * invf;
  float s, c;
  sincosf(ang, &s, &c);
  float o1 = v1 * c - v2 * s;
  float o2 = v2 * c + v1 * s;
  o1 = 1.f / (1.f + __expf(-o1));
  o2 = 1.f / (1.f + __expf(-o2));
  const u16 b1 = f2bf(o1), b2 = f2bf(o2);
  buf[base + p]      = b1;
  buf[base + p + 64] = b2;
  const float r1 = bf2f(b1), r2 = bf2f(b2);
  float ss = r1 * r1 + r2 * r2;
#pragma unroll
  for (int off = 1; off < 64; off <<= 1) ss += __shfl_xor(ss, off, 64);
  if ((threadIdx.x & 63) == 0) sq[(size_t)bh * L_SEQ + l] = ss;
}

// ======================= MFMA flash attention, fixed max=0 =======================
// scores = -(|q-k|^2)/tau <= 0; diagonal = 0 -> l >= 1. No running max/rescale.
__global__ __launch_bounds__(256)
void attn_mfma(const u16* __restrict__ Q, const u16* __restrict__ K, const u16* __restrict__ Vg,
               const float* __restrict__ qsq_g, const float* __restrict__ ksq_g,
               const float* __restrict__ taup, u16* __restrict__ Ob) {
  __shared__ __align__(16) u16 Ks[64 * 128];   // [key][d], chunk c^(key&15)
  __shared__ __align__(16) u16 Vs[128 * 64];   // [vdim][key], chunk c^(vdim&7)
  __shared__ __align__(16) u16 Ps[4][16 * 72]; // per-wave P [q][key] bf16, pitch 72
  __shared__ float ksqs[64];

  const int qt = (int)gridDim.x - 1 - (int)blockIdx.x;   // big tiles first
  const int bh = blockIdx.y;
  const int tid = threadIdx.x;
  const int wave = tid >> 6, lane = tid & 63;
  const int quad = lane >> 4, l15 = lane & 15;
  const int qBase = qt * 64;
  const int mrow = quad * 4;
  const int qg0 = qBase + wave * 16 + mrow;

  // Q A-frags (m = l15, k = quad*8+j), 4 k-blocks of 32
  const u16* Qrow = Q + ((size_t)bh * L_SEQ + qBase + wave * 16 + l15) * DHEAD;
  bf16x8 aq[4];
#pragma unroll
  for (int kb = 0; kb < 4; ++kb) aq[kb] = *(const bf16x8*)(Qrow + kb * 32 + quad * 8);

  float tau = log1pf(expf(*taup));
  tau = fminf(fmaxf(tau, 0.1f), 10.f);
  const float lt = LOG2E / tau;
  const float c2 = 2.f * lt;

  float qh[4];
#pragma unroll
  for (int r = 0; r < 4; ++r) qh[r] = qsq_g[(size_t)bh * L_SEQ + qg0 + r] * lt;

  float lst[4] = {0.f, 0.f, 0.f, 0.f};
  f32x4 oacc[8];
#pragma unroll
  for (int i = 0; i < 8; ++i) oacc[i] = (f32x4){0.f, 0.f, 0.f, 0.f};

  for (int kt = 0; kt <= qt; ++kt) {
    __syncthreads();   // prior iteration's Ks/Vs readers done
    const u16* Ktile = K + ((size_t)bh * L_SEQ + kt * 64) * DHEAD;
#pragma unroll
    for (int i = 0; i < 4; ++i) {
      const int s = (wave * 4 + i) * 64 + lane;
      const int n = s >> 4;                    // key row (16 chunks/row)
      const int c = (s & 15) ^ (n & 15);
      load_lds16(Ktile + n * DHEAD + c * 8, Ks + (size_t)(wave * 4 + i) * 512);
    }
    const u16* Vtile = Vg + (size_t)bh * DHEAD * L_SEQ + kt * 64;   // V^T rows, stride L
#pragma unroll
    for (int i = 0; i < 4; ++i) {
      const int s = (wave * 4 + i) * 64 + lane;
      const int n = s >> 3;                    // vdim row (8 chunks/row)
      const int c = (s & 7) ^ (n & 7);
      load_lds16(Vtile + (size_t)n * L_SEQ + c * 8, Vs + (size_t)(wave * 4 + i) * 512);
    }
    if (tid < 64) ksqs[tid] = ksq_g[(size_t)bh * L_SEQ + kt * 64 + tid] * lt;
    __syncthreads();   // staged data visible

    // ---- S = Q K^T ----
    f32x4 sfr[4];
#pragma unroll
    for (int nt = 0; nt < 4; ++nt) {
      f32x4 cacc = (f32x4){0.f, 0.f, 0.f, 0.f};
      const int brow = nt * 16 + l15;
#pragma unroll
      for (int kb = 0; kb < 4; ++kb) {
        const int cc = (kb * 4 + quad) ^ (brow & 15);
        const bf16x8 bf = *(const bf16x8*)(Ks + brow * 128 + cc * 8);
        cacc = __builtin_amdgcn_mfma_f32_16x16x32_bf16(aq[kb], bf, cacc, 0, 0, 0);
      }
      sfr[nt] = cacc;
    }

    // ---- p = exp2(qk*c2 - qh - kh), accumulate l, pack P (RTZ bf16) ----
    const bool diag = (kt == qt);
    u16* Pw = &Ps[wave][0];
#pragma unroll
    for (int nt = 0; nt < 4; ++nt) {
      const float kh = ksqs[nt * 16 + l15];
      const int kg = kt * 64 + nt * 16 + l15;
#pragma unroll
      for (int r = 0; r < 4; ++r) {
        float p = exp2f(sfr[nt][r] * c2 - (qh[r] + kh));
        if (diag && kg > qg0 + r) p = 0.f;
        const u32 u = __float_as_uint(p);
        lst[r] += __uint_as_float(u & 0xFFFF0000u);   // denominator from rounded P
        Pw[(mrow + r) * 72 + nt * 16 + l15] = (u16)(u >> 16);
      }
    }
    __asm__ __volatile__("s_waitcnt lgkmcnt(0)" ::: "memory");
    bf16x8 pf[2];
#pragma unroll
    for (int kb = 0; kb < 2; ++kb)
      pf[kb] = *(const bf16x8*)(Pw + l15 * 72 + kb * 32 + quad * 8);

    // ---- O += P V ----
#pragma unroll
    for (int ot = 0; ot < 8; ++ot) {
#pragma unroll
      for (int kb = 0; kb < 2; ++kb) {
        const int cc = (kb * 4 + quad) ^ (l15 & 7);   // (ot*16+l15)&7 == l15&7
        const bf16x8 vf = *(const bf16x8*)(Vs + (ot * 16 + l15) * 64 + cc * 8);
        oacc[ot] = __builtin_amdgcn_mfma_f32_16x16x32_bf16(pf[kb], vf, oacc[ot], 0, 0, 0);
      }
    }
  }

  // ---- final l reduction across the 16 key-lanes, write O ----
#pragma unroll
  for (int off = 1; off < 16; off <<= 1)
#pragma unroll
    for (int r = 0; r < 4; ++r) lst[r] += __shfl_xor(lst[r], off, 64);

  const int b = bh >> 4, hh = bh & 15;
#pragma unroll
  for (int r = 0; r < 4; ++r) {
    const float invl = 1.f / lst[r];
    const int qg = qg0 + r;
    u16* dst = Ob + ((size_t)(b * L_SEQ + qg)) * D_MODEL + hh * DHEAD;
#pragma unroll
    for (int ot = 0; ot < 8; ++ot)
      dst[ot * 16 + l15] = f2bf(oacc[ot][r] * invl);
  }
}

// ======================= launch =======================
extern "C" void kernel_launch(void* const* d_in, const int* in_sizes, int n_in,
                              void* d_out, int out_size, void* d_ws, size_t ws_size,
                              hipStream_t stream) {
  const float* x     = (const float*)d_in[0];
  const float* Wq    = (const float*)d_in[1];
  const float* Wk    = (const float*)d_in[2];
  const float* Wv    = (const float*)d_in[3];
  const float* Wo    = (const float*)d_in[4];
  const float* tau_p = (const float*)d_in[5];

  const size_t NX = (size_t)M_ROWS * D_MODEL;
  const size_t NW = (size_t)D_MODEL * D_MODEL;
  u16* xb  = (u16*)d_ws;                  // aliased as Obuf after projections
  u16* Wqb = xb  + NX;
  u16* Wkb = Wqb + NW;
  u16* Wvb = Wkb + NW;
  u16* Wob = Wvb + NW;
  u16* Qb  = Wob + NW;
  u16* Kb  = Qb + NX;
  u16* Vtb = Kb + NX;                     // V^T (B,H,d,L)
  float* qsq = (float*)(Vtb + NX);
  float* ksq = qsq + (size_t)NBH * L_SEQ;
  u16* Obuf = xb;

  cast_all<<<dim3((int)(NX / 4 / 256), 5), 256, 0, stream>>>(
      x, Wq, Wk, Wv, Wo, xb, Wqb, Wkb, Wvb, Wob);

  gemm_qkv<<<dim3(M_ROWS / 128, 48), 256, 0, stream>>>(xb, Wqb, Wkb, Wvb, Qb, Kb, Vtb);

  rope_sig<<<dim3((NBH * L_SEQ * 64) / 256, 2), 256, 0, stream>>>(Qb, Kb, qsq, ksq);

  attn_mfma<<<dim3(L_SEQ / 64, NBH), 256, 0, stream>>>(Qb, Kb, Vtb, qsq, ksq, tau_p, Obuf);

  gemm_out<<<dim3(M_ROWS / 128, D_MODEL / 128), 256, 0, stream>>>(Obuf, Wob, (float*)d_out);
}

// Round 4
// 767.544 us; speedup vs baseline: 8.8082x; 1.0737x over previous
//
#include <hip/hip_runtime.h>
#include <cstddef>

typedef unsigned short u16;
typedef unsigned int   u32;
typedef short  bf16x8 __attribute__((ext_vector_type(8)));
typedef float  f32x4  __attribute__((ext_vector_type(4)));

#define L_SEQ   2048
#define D_MODEL 2048
#define NHEADS  16
#define DHEAD   128
#define NBH     64
#define M_ROWS  8192
#define LOG2E   1.4426950408889634f

__device__ __forceinline__ u16 f2bf(float f) {
  u32 u = __float_as_uint(f);
  u32 r = (u + 0x7FFFu + ((u >> 16) & 1u)) >> 16;   // RNE; inputs finite
  return (u16)r;
}
__device__ __forceinline__ float bf2f(u16 u) {
  return __uint_as_float(((u32)u) << 16);
}
__device__ __forceinline__ void load_lds16(const u16* g, u16* l) {
  __builtin_amdgcn_global_load_lds((const __attribute__((address_space(1))) u32*)g,
                                   (__attribute__((address_space(3))) u32*)l, 16, 0, 0);
}

// ======================= fused fp32 -> bf16 casts =======================
__global__ __launch_bounds__(256)
void cast_all(const float* __restrict__ x,
              const float* __restrict__ wq, const float* __restrict__ wk,
              const float* __restrict__ wv, const float* __restrict__ wo,
              u16* __restrict__ xb, u16* __restrict__ wqb, u16* __restrict__ wkb,
              u16* __restrict__ wvb, u16* __restrict__ wob) {
  const int y = blockIdx.y;
  const float* s; u16* d; int n4;
  const int NX4 = M_ROWS * D_MODEL / 4;
  const int W4  = D_MODEL * D_MODEL / 4;
  switch (y) {
    case 0: s = x;  d = xb;  n4 = NX4; break;
    case 1: s = wq; d = wqb; n4 = W4;  break;
    case 2: s = wk; d = wkb; n4 = W4;  break;
    case 3: s = wv; d = wvb; n4 = W4;  break;
    default: s = wo; d = wob; n4 = W4; break;
  }
  int i = blockIdx.x * 256 + threadIdx.x;
  if (i >= n4) return;
  float4 v = ((const float4*)s)[i];
  ushort4 o;
  o.x = f2bf(v.x); o.y = f2bf(v.y); o.z = f2bf(v.z); o.w = f2bf(v.w);
  ((ushort4*)d)[i] = o;
}

// ======================= GEMM core: 128x128 tile, BK=64, bf16 MFMA =======================
__device__ __forceinline__ void gemm_core(const u16* __restrict__ A, const u16* __restrict__ W,
                                          u16* As, u16* Bs, int rBase, int cBase,
                                          f32x4 (&acc)[4][4]) {
  const int tid  = threadIdx.x;
  const int wave = tid >> 6, lane = tid & 63;
  const int quad = lane >> 4, l15 = lane & 15;
  const int wr = wave >> 1, wc = wave & 1;

#pragma unroll
  for (int m = 0; m < 4; ++m)
#pragma unroll
    for (int n = 0; n < 4; ++n) acc[m][n] = (f32x4){0.f, 0.f, 0.f, 0.f};

  for (int kb = 0; kb < D_MODEL; kb += 64) {
    __syncthreads();
#pragma unroll
    for (int i = 0; i < 4; ++i) {
      const int s = (wave * 4 + i) * 64 + lane;
      const int n = s >> 3;
      const int c = (s & 7) ^ (n & 7);
      load_lds16(A + (size_t)(rBase + n) * D_MODEL + kb + c * 8,
                 As + (size_t)(wave * 4 + i) * 512);
      load_lds16(W + (size_t)(cBase + n) * D_MODEL + kb + c * 8,
                 Bs + (size_t)(wave * 4 + i) * 512);
    }
    __syncthreads();
#pragma unroll
    for (int h = 0; h < 2; ++h) {
      bf16x8 af[4], bfr[4];
#pragma unroll
      for (int m = 0; m < 4; ++m) {
        const int row = wr * 64 + m * 16 + l15;
        const int cc = (h * 4 + quad) ^ (row & 7);
        af[m] = *(const bf16x8*)(As + row * 64 + cc * 8);
      }
#pragma unroll
      for (int n = 0; n < 4; ++n) {
        const int row = wc * 64 + n * 16 + l15;
        const int cc = (h * 4 + quad) ^ (row & 7);
        bfr[n] = *(const bf16x8*)(Bs + row * 64 + cc * 8);
      }
#pragma unroll
      for (int m = 0; m < 4; ++m)
#pragma unroll
        for (int n = 0; n < 4; ++n)
          acc[m][n] = __builtin_amdgcn_mfma_f32_16x16x32_bf16(af[m], bfr[n], acc[m][n], 0, 0, 0);
    }
  }
}

// ======================= fused QKV projection + RoPE/sigmoid =======================
// grid (M/128, 48): seg = y>>4 (0:Q 1:K 2:V), head h = y&15.
// Q,K -> rope+sigmoid applied, stored (B,H,L,d) bf16, square-sums to qsq/ksq.
// V -> V^T (B,H,d,L) bf16.
#define TP 136   // epilogue LDS tile pitch (u16)
__global__ __launch_bounds__(256)
void gemm_qkv(const u16* __restrict__ A,
              const u16* __restrict__ Wq, const u16* __restrict__ Wk, const u16* __restrict__ Wv,
              u16* __restrict__ Qo, u16* __restrict__ Ko, u16* __restrict__ Vt,
              float* __restrict__ qsq, float* __restrict__ ksq) {
  __shared__ __align__(16) u16 buf[128 * TP];
  u16* As = buf;
  u16* Bs = buf + 8192;

  const int tid  = threadIdx.x;
  const int wave = tid >> 6, lane = tid & 63;
  const int quad = lane >> 4, l15 = lane & 15;
  const int wr = wave >> 1, wc = wave & 1;
  const int rBase = blockIdx.x << 7;
  const int seg = blockIdx.y >> 4;
  const int h   = blockIdx.y & 15;
  const int cBase = h << 7;
  const u16* W = (seg == 0) ? Wq : (seg == 1) ? Wk : Wv;

  f32x4 acc[4][4];
  gemm_core(A, W, As, Bs, rBase, cBase, acc);

  __syncthreads();   // main loop LDS reads done; reuse buf
  if (seg < 2) {
    // tile T[l_loc][p]
#pragma unroll
    for (int m = 0; m < 4; ++m)
#pragma unroll
      for (int n = 0; n < 4; ++n) {
        const int l0 = wr * 64 + m * 16 + quad * 4;
        const int p  = wc * 64 + n * 16 + l15;
#pragma unroll
        for (int r = 0; r < 4; ++r)
          buf[(l0 + r) * TP + p] = f2bf(acc[m][n][r]);
      }
    __syncthreads();

    // RoPE + sigmoid + square-sums, then store.
    const int row = tid >> 1, sel = tid & 1;
    const int p0 = sel * 32;
    const int token = rBase + row;
    const int b = token >> 11, l = token & 2047;
    u16* base = (seg == 0) ? Qo : Ko;
    float* sq = (seg == 0) ? qsq : ksq;
    u16* dst = base + ((size_t)(b * NHEADS + h) * L_SEQ + l) * DHEAD;
    float ss = 0.f;
#pragma unroll
    for (int c4 = 0; c4 < 4; ++c4) {
      const bf16x8 a  = *(const bf16x8*)&buf[row * TP + p0 + c4 * 8];
      const bf16x8 bb = *(const bf16x8*)&buf[row * TP + p0 + c4 * 8 + 64];
      bf16x8 out1, out2;
#pragma unroll
      for (int j = 0; j < 8; ++j) {
        const int p = p0 + c4 * 8 + j;
        const float v1 = bf2f((u16)a[j]);
        const float v2 = bf2f((u16)bb[j]);
        const float invf = exp2f(-(float)p * (13.287712379549449f / 64.f));
        const float ang = (float)l * invf;
        float s, c;
        sincosf(ang, &s, &c);
        float o1 = v1 * c - v2 * s;
        float o2 = v2 * c + v1 * s;
        o1 = 1.f / (1.f + __expf(-o1));
        o2 = 1.f / (1.f + __expf(-o2));
        const u16 b1 = f2bf(o1), b2 = f2bf(o2);
        out1[j] = (short)b1; out2[j] = (short)b2;
        const float r1 = bf2f(b1), r2 = bf2f(b2);
        ss += r1 * r1 + r2 * r2;
      }
      *(bf16x8*)(dst + p0 + c4 * 8) = out1;
      *(bf16x8*)(dst + p0 + 64 + c4 * 8) = out2;
    }
    ss += __shfl_xor(ss, 1, 64);
    if (sel == 0) sq[(size_t)(b * NHEADS + h) * L_SEQ + l] = ss;
  } else {
    // V: T[p_loc][l_loc], b64-packed
#pragma unroll
    for (int m = 0; m < 4; ++m)
#pragma unroll
      for (int n = 0; n < 4; ++n) {
        const int l0 = wr * 64 + m * 16 + quad * 4;
        const int p  = wc * 64 + n * 16 + l15;
        uint2 pk;
        pk.x = (u32)f2bf(acc[m][n][0]) | ((u32)f2bf(acc[m][n][1]) << 16);
        pk.y = (u32)f2bf(acc[m][n][2]) | ((u32)f2bf(acc[m][n][3]) << 16);
        *(uint2*)&buf[p * TP + l0] = pk;
      }
    __syncthreads();
    const int row = tid >> 1, hf = tid & 1;
    const u16* src = buf + row * TP + hf * 64;
    const int b = rBase >> 11, l0 = (rBase & 2047) + hf * 64;
    u16* dst = Vt + ((size_t)(b * NHEADS + h) * DHEAD + row) * L_SEQ + l0;
#pragma unroll
    for (int c = 0; c < 8; ++c)
      *(bf16x8*)(dst + c * 8) = *(const bf16x8*)(src + c * 8);
  }
}

// ======================= output projection: C = A * Wo^T (f32 out) =======================
__global__ __launch_bounds__(256)
void gemm_out(const u16* __restrict__ A, const u16* __restrict__ W, float* __restrict__ C) {
  __shared__ __align__(16) u16 As[128 * 64];
  __shared__ __align__(16) u16 Bs[128 * 64];
  const int tid  = threadIdx.x;
  const int wave = tid >> 6, lane = tid & 63;
  const int quad = lane >> 4, l15 = lane & 15;
  const int wr = wave >> 1, wc = wave & 1;
  const int rBase = blockIdx.x << 7;
  const int cBase = blockIdx.y << 7;

  f32x4 acc[4][4];
  gemm_core(A, W, As, Bs, rBase, cBase, acc);

#pragma unroll
  for (int m = 0; m < 4; ++m)
#pragma unroll
    for (int n = 0; n < 4; ++n) {
      const int row0 = rBase + wr * 64 + m * 16 + quad * 4;
      const int col  = cBase + wc * 64 + n * 16 + l15;
#pragma unroll
      for (int r = 0; r < 4; ++r)
        C[(size_t)(row0 + r) * D_MODEL + col] = acc[m][n][r];
    }
}

// ======================= MFMA flash attention, BQ=128, fixed max=0 =======================
// scores = -|q-k|^2/tau <= 0; diagonal = 0 -> l >= 1. Each wave: 32 q rows.
__global__ __launch_bounds__(256)
void attn_mfma(const u16* __restrict__ Q, const u16* __restrict__ K, const u16* __restrict__ Vg,
               const float* __restrict__ qsq_g, const float* __restrict__ ksq_g,
               const float* __restrict__ taup, u16* __restrict__ Ob) {
  __shared__ __align__(16) u16 Ks[64 * 128];   // [key][d], chunk c^(key&15)
  __shared__ __align__(16) u16 Vs[128 * 64];   // [vdim][key], chunk c^(vdim&7)
  __shared__ __align__(16) u16 Ps[4][32 * 72]; // per-wave P [q][key] bf16, pitch 72
  __shared__ float ksqs[64];

  const int qt = (int)gridDim.x - 1 - (int)blockIdx.x;   // big tiles first
  const int bh = blockIdx.y;
  const int tid = threadIdx.x;
  const int wave = tid >> 6, lane = tid & 63;
  const int quad = lane >> 4, l15 = lane & 15;
  const int qBase = qt * 128;
  const int mrow = quad * 4;

  // Q A-frags for 2 m-tiles (m = l15, k = quad*8+j)
  bf16x8 aq[2][4];
#pragma unroll
  for (int mt = 0; mt < 2; ++mt) {
    const u16* Qrow = Q + ((size_t)bh * L_SEQ + qBase + wave * 32 + mt * 16 + l15) * DHEAD;
#pragma unroll
    for (int kb = 0; kb < 4; ++kb) aq[mt][kb] = *(const bf16x8*)(Qrow + kb * 32 + quad * 8);
  }

  float tau = log1pf(expf(*taup));
  tau = fminf(fmaxf(tau, 0.1f), 10.f);
  const float lt = LOG2E / tau;
  const float c2 = 2.f * lt;

  float qh[2][4];
#pragma unroll
  for (int mt = 0; mt < 2; ++mt)
#pragma unroll
    for (int r = 0; r < 4; ++r)
      qh[mt][r] = qsq_g[(size_t)bh * L_SEQ + qBase + wave * 32 + mt * 16 + mrow + r] * lt;

  float lst[2][4] = {{0.f, 0.f, 0.f, 0.f}, {0.f, 0.f, 0.f, 0.f}};
  f32x4 oacc[2][8];
#pragma unroll
  for (int mt = 0; mt < 2; ++mt)
#pragma unroll
    for (int i = 0; i < 8; ++i) oacc[mt][i] = (f32x4){0.f, 0.f, 0.f, 0.f};

  const int ktmax = 2 * qt + 1;
  for (int kt = 0; kt <= ktmax; ++kt) {
    __syncthreads();   // prior iteration's Ks/Vs readers done
    const u16* Ktile = K + ((size_t)bh * L_SEQ + kt * 64) * DHEAD;
#pragma unroll
    for (int i = 0; i < 4; ++i) {
      const int s = (wave * 4 + i) * 64 + lane;
      const int n = s >> 4;
      const int c = (s & 15) ^ (n & 15);
      load_lds16(Ktile + n * DHEAD + c * 8, Ks + (size_t)(wave * 4 + i) * 512);
    }
    const u16* Vtile = Vg + (size_t)bh * DHEAD * L_SEQ + kt * 64;
#pragma unroll
    for (int i = 0; i < 4; ++i) {
      const int s = (wave * 4 + i) * 64 + lane;
      const int n = s >> 3;
      const int c = (s & 7) ^ (n & 7);
      load_lds16(Vtile + (size_t)n * L_SEQ + c * 8, Vs + (size_t)(wave * 4 + i) * 512);
    }
    if (tid < 64) ksqs[tid] = ksq_g[(size_t)bh * L_SEQ + kt * 64 + tid] * lt;
    __syncthreads();   // staged data visible

    u16* Pw = &Ps[wave][0];
    const bool diag = (kt >= 2 * qt);
#pragma unroll
    for (int mt = 0; mt < 2; ++mt) {
      // ---- S = Q K^T for this m-tile ----
      f32x4 sfr[4];
#pragma unroll
      for (int nt = 0; nt < 4; ++nt) {
        f32x4 cacc = (f32x4){0.f, 0.f, 0.f, 0.f};
        const int brow = nt * 16 + l15;
#pragma unroll
        for (int kb = 0; kb < 4; ++kb) {
          const int cc = (kb * 4 + quad) ^ l15;
          const bf16x8 bf = *(const bf16x8*)(Ks + brow * 128 + cc * 8);
          cacc = __builtin_amdgcn_mfma_f32_16x16x32_bf16(aq[mt][kb], bf, cacc, 0, 0, 0);
        }
        sfr[nt] = cacc;
      }
      // ---- p = exp2(qk*c2 - qh - kh), accumulate l, pack P (RTZ bf16) ----
      const int qg0m = qBase + wave * 32 + mt * 16 + mrow;
#pragma unroll
      for (int nt = 0; nt < 4; ++nt) {
        const float kh = ksqs[nt * 16 + l15];
        const int kg = kt * 64 + nt * 16 + l15;
#pragma unroll
        for (int r = 0; r < 4; ++r) {
          float p = exp2f(sfr[nt][r] * c2 - (qh[mt][r] + kh));
          if (diag && kg > qg0m + r) p = 0.f;
          const u32 u = __float_as_uint(p);
          lst[mt][r] += __uint_as_float(u & 0xFFFF0000u);
          Pw[(mt * 16 + mrow + r) * 72 + nt * 16 + l15] = (u16)(u >> 16);
        }
      }
    }
    __asm__ __volatile__("s_waitcnt lgkmcnt(0)" ::: "memory");
    bf16x8 pf[2][2];
#pragma unroll
    for (int mt = 0; mt < 2; ++mt)
#pragma unroll
      for (int kb = 0; kb < 2; ++kb)
        pf[mt][kb] = *(const bf16x8*)(Pw + (mt * 16 + l15) * 72 + kb * 32 + quad * 8);

    // ---- O += P V (V B-frags shared across both m-tiles) ----
#pragma unroll
    for (int ot = 0; ot < 8; ++ot) {
#pragma unroll
      for (int kb = 0; kb < 2; ++kb) {
        const int cc = (kb * 4 + quad) ^ (l15 & 7);
        const bf16x8 vf = *(const bf16x8*)(Vs + (ot * 16 + l15) * 64 + cc * 8);
#pragma unroll
        for (int mt = 0; mt < 2; ++mt)
          oacc[mt][ot] = __builtin_amdgcn_mfma_f32_16x16x32_bf16(pf[mt][kb], vf, oacc[mt][ot], 0, 0, 0);
      }
    }
  }

  // ---- final l reduction across the 16 key-lanes, write O ----
#pragma unroll
  for (int off = 1; off < 16; off <<= 1)
#pragma unroll
    for (int mt = 0; mt < 2; ++mt)
#pragma unroll
      for (int r = 0; r < 4; ++r) lst[mt][r] += __shfl_xor(lst[mt][r], off, 64);

  const int b = bh >> 4, hh = bh & 15;
#pragma unroll
  for (int mt = 0; mt < 2; ++mt)
#pragma unroll
    for (int r = 0; r < 4; ++r) {
      const float invl = 1.f / lst[mt][r];
      const int qg = qBase + wave * 32 + mt * 16 + mrow + r;
      u16* dst = Ob + ((size_t)(b * L_SEQ + qg)) * D_MODEL + hh * DHEAD;
#pragma unroll
      for (int ot = 0; ot < 8; ++ot)
        dst[ot * 16 + l15] = f2bf(oacc[mt][ot][r] * invl);
    }
}

// ======================= launch =======================
extern "C" void kernel_launch(void* const* d_in, const int* in_sizes, int n_in,
                              void* d_out, int out_size, void* d_ws, size_t ws_size,
                              hipStream_t stream) {
  const float* x     = (const float*)d_in[0];
  const float* Wq    = (const float*)d_in[1];
  const float* Wk    = (const float*)d_in[2];
  const float* Wv    = (const float*)d_in[3];
  const float* Wo    = (const float*)d_in[4];
  const float* tau_p = (const float*)d_in[5];

  const size_t NX = (size_t)M_ROWS * D_MODEL;
  const size_t NW = (size_t)D_MODEL * D_MODEL;
  u16* xb  = (u16*)d_ws;                  // aliased as Obuf after projections
  u16* Wqb = xb  + NX;
  u16* Wkb = Wqb + NW;
  u16* Wvb = Wkb + NW;
  u16* Wob = Wvb + NW;
  u16* Qb  = Wob + NW;
  u16* Kb  = Qb + NX;
  u16* Vtb = Kb + NX;                     // V^T (B,H,d,L)
  float* qsq = (float*)(Vtb + NX);
  float* ksq = qsq + (size_t)NBH * L_SEQ;
  u16* Obuf = xb;

  cast_all<<<dim3((int)(NX / 4 / 256), 5), 256, 0, stream>>>(
      x, Wq, Wk, Wv, Wo, xb, Wqb, Wkb, Wvb, Wob);

  gemm_qkv<<<dim3(M_ROWS / 128, 48), 256, 0, stream>>>(
      xb, Wqb, Wkb, Wvb, Qb, Kb, Vtb, qsq, ksq);

  attn_mfma<<<dim3(L_SEQ / 128, NBH), 256, 0, stream>>>(Qb, Kb, Vtb, qsq, ksq, tau_p, Obuf);

  gemm_out<<<dim3(M_ROWS / 128, D_MODEL / 128), 256, 0, stream>>>(Obuf, Wob, (float*)d_out);
}